// Round 5
// baseline (1182.902 us; speedup 1.0000x reference)
//
#include <hip/hip_runtime.h>
#include <hip/hip_cooperative_groups.h>
#include <math.h>

namespace cg = cooperative_groups;

// Problem constants (fixed by the reference setup_inputs)
#define BB 32
#define PP 24564
#define OO 16
#define CC 81
#define BP (BB * PP)
#define CHUNK 1024
#define NCHK ((PP + CHUNK - 1) / CHUNK)   // 24
#define NMATCH (NCHK * BB)                // 768
#define NTILE (BP / 64)                   // 12282
#define NSB 512                           // select sub-blocks: 64 tasks x 8

typedef unsigned long long ull;

__device__ __forceinline__ float sl1(float x) {
    float ax = fabsf(x);
    return ax < 1.0f ? 0.5f * ax * ax : ax - 0.5f;
}

// unaligned-by-16 (4B-aligned) float4 global load: conf row stride is 324 B
__device__ __forceinline__ float4 ld4u(const float* p) {
    float4 v;
    __builtin_memcpy(&v, p, 16);
    return v;
}

__device__ __forceinline__ float ald(const float* p) {
    return __hip_atomic_load(p, __ATOMIC_RELAXED, __HIP_MEMORY_SCOPE_AGENT);
}
__device__ __forceinline__ int aldi(const int* p) {
    return __hip_atomic_load(p, __ATOMIC_RELAXED, __HIP_MEMORY_SCOPE_AGENT);
}

// ---------------------------------------------------------------------------
// Mega-kernel: all phases fused, ordered by grid.sync().
//  P1: per-(batch,truth) best prior (packed-key atomicMax)
//  P2: LSE + mining + positive losses (no LDS, quartet-per-row, direct global)
//  P3: top-k sums via 4-pass radix select, 8 sub-blocks per (arr,batch) task
//  P4: final scalars (block 0)
// Sync contract: cross-block handoffs via __threadfence + grid.sync; the
// gstate chain (selection -> next accumulate) is INTRA-block only (each block
// consumes gstate entries it wrote itself; identical redundant writes across
// blocks), ordered by a __syncthreads() at the end of each pass.  <- v5 fix
// ---------------------------------------------------------------------------
__global__ __launch_bounds__(256, 4) void k_mega(
        const float* __restrict__ conf, const float* __restrict__ obj,
        const float* __restrict__ loc, const float* __restrict__ priors,
        const float* __restrict__ truths, const int* __restrict__ labels,
        ull* __restrict__ best_prior,   // [BB*OO] zeroed
        float* __restrict__ mining,     // [2*BP]
        int* __restrict__ num_posS,     // [16][BB] zeroed
        float* __restrict__ acc,        // [8] zeroed; [3]=neg_obj [4]=neg_c
        float* __restrict__ accS,       // [128][32] zeroed
        unsigned* __restrict__ ghist,   // [4][64][256] zeroed
        ull* __restrict__ gstate,       // [2][64] zeroed
        float* __restrict__ out) {
    const int tid = threadIdx.x;
    const int bid = blockIdx.x;
    const int nblk = gridDim.x;
    cg::grid_group grid = cg::this_grid();

    __shared__ float s_tr[OO][4];
    __shared__ float s_ta[OO];
    __shared__ ull s_red[4][OO];
    __shared__ unsigned s_histw[4][256];
    __shared__ unsigned s_bins[256];
    __shared__ float s_ws[4];
    __shared__ unsigned s_wc[4];

    // ---------------- P1: best prior per (batch, truth) ----------------
    for (int task = bid; task < NMATCH; task += nblk) {
        const int b = task / NCHK;
        const int c = task - b * NCHK;
        __syncthreads();                      // WAR guard on s_tr across iters
        if (tid < OO * 4) ((float*)s_tr)[tid] = truths[b * OO * 4 + tid];
        __syncthreads();
        if (tid < OO)
            s_ta[tid] = (s_tr[tid][2] - s_tr[tid][0]) * (s_tr[tid][3] - s_tr[tid][1]);
        __syncthreads();

        float bpv[OO];
        int bpi[OO];
#pragma unroll
        for (int o = 0; o < OO; o++) { bpv[o] = -1.0f; bpi[o] = -1; }

        const int p0 = c * CHUNK;
        const int pend = (p0 + CHUNK < PP) ? p0 + CHUNK : PP;
        for (int p = p0 + tid; p < pend; p += 256) {
            const float4 pr = ((const float4*)priors)[p];
            const float x1 = pr.x - pr.z * 0.5f, y1 = pr.y - pr.w * 0.5f;
            const float x2 = pr.x + pr.z * 0.5f, y2 = pr.y + pr.w * 0.5f;
            const float parea = (x2 - x1) * (y2 - y1);
#pragma unroll
            for (int o = 0; o < OO; o++) {
                const float lx = fmaxf(s_tr[o][0], x1), ly = fmaxf(s_tr[o][1], y1);
                const float rx = fminf(s_tr[o][2], x2), ry = fminf(s_tr[o][3], y2);
                const float iw = fmaxf(rx - lx, 0.0f), ih = fmaxf(ry - ly, 0.0f);
                const float inter = iw * ih;
                const float iou = inter / (s_ta[o] + parea - inter);
                if (iou > bpv[o]) { bpv[o] = iou; bpi[o] = p; }
            }
        }

        const int wave = tid >> 6;
        const int lane = tid & 63;
#pragma unroll
        for (int o = 0; o < OO; o++) {
            ull key = (bpi[o] >= 0)
                ? (((ull)__float_as_uint(bpv[o]) << 32) |
                   (ull)(0xFFFFFFFFu - (unsigned)bpi[o]))
                : 0ull;
#pragma unroll
            for (int d = 32; d; d >>= 1) {
                const ull other = __shfl_xor(key, d);
                key = (other > key) ? other : key;
            }
            if (lane == 0) s_red[wave][o] = key;
        }
        __syncthreads();
        if (tid < OO) {
            const ull k0 = s_red[0][tid], k1 = s_red[1][tid];
            const ull k2 = s_red[2][tid], k3 = s_red[3][tid];
            ull m = k0 > k1 ? k0 : k1;
            const ull m2 = k2 > k3 ? k2 : k3;
            m = m > m2 ? m : m2;
            if (m != 0ull) atomicMax(&best_prior[b * OO + tid], m);
        }
    }

    __threadfence();
    grid.sync();

    // ---------------- P2: LSE + mining + positive losses ----------------
    for (int tile = bid; tile < NTILE; tile += nblk) {
        const int row0 = tile * 64;
        const int r = tid >> 2;
        const int part = tid & 3;
        const int row = row0 + r;
        const float* rowp = conf + (size_t)row * CC;
        const int c0 = part * 20;

        const float4 v0 = ld4u(rowp + c0);
        const float4 v1 = ld4u(rowp + c0 + 4);
        const float4 v2 = ld4u(rowp + c0 + 8);
        const float4 v3 = ld4u(rowp + c0 + 12);
        const float4 v4 = ld4u(rowp + c0 + 16);
        const float ex = (part == 3) ? rowp[80] : 0.0f;

        float m = v0.x;
        m = fmaxf(m, v0.y); m = fmaxf(m, v0.z); m = fmaxf(m, v0.w);
        m = fmaxf(m, v1.x); m = fmaxf(m, v1.y); m = fmaxf(m, v1.z); m = fmaxf(m, v1.w);
        m = fmaxf(m, v2.x); m = fmaxf(m, v2.y); m = fmaxf(m, v2.z); m = fmaxf(m, v2.w);
        m = fmaxf(m, v3.x); m = fmaxf(m, v3.y); m = fmaxf(m, v3.z); m = fmaxf(m, v3.w);
        m = fmaxf(m, v4.x); m = fmaxf(m, v4.y); m = fmaxf(m, v4.z); m = fmaxf(m, v4.w);
        if (part == 3) m = fmaxf(m, ex);
        m = fmaxf(m, __shfl_xor(m, 1));
        m = fmaxf(m, __shfl_xor(m, 2));

        float s = 0.0f;
        s += __expf(v0.x - m); s += __expf(v0.y - m); s += __expf(v0.z - m); s += __expf(v0.w - m);
        s += __expf(v1.x - m); s += __expf(v1.y - m); s += __expf(v1.z - m); s += __expf(v1.w - m);
        s += __expf(v2.x - m); s += __expf(v2.y - m); s += __expf(v2.z - m); s += __expf(v2.w - m);
        s += __expf(v3.x - m); s += __expf(v3.y - m); s += __expf(v3.z - m); s += __expf(v3.w - m);
        s += __expf(v4.x - m); s += __expf(v4.y - m); s += __expf(v4.z - m); s += __expf(v4.w - m);
        if (part == 3) s += __expf(ex - m);
        s += __shfl_xor(s, 1);
        s += __shfl_xor(s, 2);
        const float lse = m + __logf(s);

        const int b = row / PP;
        bool pos = false;
        float my_l = 0.0f, my_co = 0.0f, my_cc = 0.0f;
        if (part == 0) {
            const int p = row - b * PP;
            const float4 pr = ((const float4*)priors)[p];
            const float x1 = pr.x - pr.z * 0.5f, y1 = pr.y - pr.w * 0.5f;
            const float x2 = pr.x + pr.z * 0.5f, y2 = pr.y + pr.w * 0.5f;
            const float parea = (x2 - x1) * (y2 - y1);
            float best = -1.0f;
            int ti = 0;
            const float4* trb = (const float4*)truths + b * OO;
#pragma unroll
            for (int o = 0; o < OO; o++) {
                const float4 t = trb[o];
                const float ta = (t.z - t.x) * (t.w - t.y);
                const float lx = fmaxf(t.x, x1), ly = fmaxf(t.y, y1);
                const float rx = fminf(t.z, x2), ry = fminf(t.w, y2);
                const float iw = fmaxf(rx - lx, 0.0f), ih = fmaxf(ry - ly, 0.0f);
                const float inter = iw * ih;
                const float iou = inter / (ta + parea - inter);
                if (iou > best) { best = iou; ti = o; }
            }
            float ov = best;
#pragma unroll
            for (int o = 0; o < OO; o++) {     // ascending o = last-writer-wins
                const unsigned fp = 0xFFFFFFFFu -
                    (unsigned)(best_prior[b * OO + o] & 0xFFFFFFFFull);
                if (fp == (unsigned)p) { ti = o; ov = 2.0f; }
            }

            const int lbl = labels[b * OO + ti];
            const int tgt = (ov < 0.5f) ? 0 : lbl;
            const float ce_c = lse - rowp[tgt];

            const float2 o2 = ((const float2*)obj)[row];
            const float mo = fmaxf(o2.x, o2.y);
            const float lse_o = mo + __logf(__expf(o2.x - mo) + __expf(o2.y - mo));
            pos = tgt > 0;
            const float ce_o = lse_o - (pos ? o2.y : o2.x);

            mining[BP + row] = pos ? 0.0f : ce_c;   // mining_c
            mining[row]      = pos ? 0.0f : ce_o;   // mining_obj

            if (pos) {
                my_co = ce_o;
                my_cc = ce_c;
                const float4 t = trb[ti];
                const float gcx = ((t.x + t.z) * 0.5f - pr.x) / (0.1f * pr.z);
                const float gcy = ((t.y + t.w) * 0.5f - pr.y) / (0.1f * pr.w);
                const float gw = logf((t.z - t.x) / pr.z) / 0.2f;
                const float gh = logf((t.w - t.y) / pr.w) / 0.2f;
                const float4 ld = ((const float4*)loc)[row];
                my_l = sl1(ld.x - gcx) + sl1(ld.y - gcy) +
                       sl1(ld.z - gw) + sl1(ld.w - gh);
            }
        }

        const int lane = tid & 63;
        const int w = tid >> 6;
        const ull mpos = __ballot(pos);
        const int bw0 = __shfl(b, 0);
        const ull mb1 = __ballot(b != bw0);
#pragma unroll
        for (int d = 32; d; d >>= 1) {
            my_l  += __shfl_down(my_l,  d);
            my_co += __shfl_down(my_co, d);
            my_cc += __shfl_down(my_cc, d);
        }
        if (lane == 0 && mpos) {
            const int stripe = tile * 4 + w;
            const int cnt0 = __popcll(mpos & ~mb1);
            const int cnt1 = __popcll(mpos &  mb1);
            int* nps = num_posS + (stripe & 15) * BB;
            if (cnt0) atomicAdd(&nps[bw0], cnt0);
            if (cnt1) atomicAdd(&nps[bw0 + 1], cnt1);
            float* slot = accS + (size_t)(stripe & 127) * 32;
            atomicAdd(slot + 0, my_l);
            atomicAdd(slot + 1, my_co);
            atomicAdd(slot + 2, my_cc);
        }
    }

    __threadfence();
    grid.sync();

    // ---------------- P3: 4-pass radix select, 8 sub-blocks/task ----------
    for (int pass = 0; pass < 4; pass++) {
        const int shift = 24 - pass * 8;
        // accumulate
        for (int sb = bid; sb < NSB; sb += nblk) {
            const int task = sb >> 3, sub = sb & 7;
            const int arr = task >> 5, b = task & 31;
            unsigned prefix = 0;
            bool active = true;
            if (pass > 0) {
                const ull st = gstate[((pass - 1) & 1) * 64 + task];
                prefix = (unsigned)(st >> 32);
                if ((int)(st & 0xFFFFFFFFull) <= 0) active = false;
            }
            __syncthreads();                 // WAR on s_histw across iters
            for (int i = tid; i < 1024; i += 256) ((unsigned*)s_histw)[i] = 0u;
            __syncthreads();
            if (active) {
                const float* x = mining + ((size_t)arr * BB + b) * PP;
                const unsigned pmask = (pass == 0) ? 0u : (0xFFFFFFFFu << (shift + 8));
                const int wv = tid >> 6;
#pragma unroll
                for (int j = 0; j < 12; j++) {
                    const int i = j * 2048 + sub * 256 + tid;
                    if (i < PP) {
                        const unsigned u = __float_as_uint(x[i]);
                        if ((u & pmask) == prefix)
                            atomicAdd(&s_histw[wv][(u >> shift) & 255u], 1u);
                    }
                }
            }
            __syncthreads();
            {
                const unsigned sum = s_histw[0][tid & 255] + s_histw[1][tid & 255] +
                                     s_histw[2][tid & 255] + s_histw[3][tid & 255];
                if (sum) atomicAdd(&ghist[((size_t)pass * 64 + task) * 256 + (tid & 255)], sum);
            }
        }
        __threadfence();
        grid.sync();
        // selection (redundant per serving block; identical-value writes)
        for (int sb = bid; sb < NSB; sb += nblk) {
            const int task = sb >> 3;
            __syncthreads();                 // WAR on s_bins across iters
            s_bins[tid & 255] = ghist[((size_t)pass * 64 + task) * 256 + (tid & 255)];
            __syncthreads();
            if (tid == 0) {
                int krem;
                unsigned prefix;
                if (pass == 0) {
                    const int b = task & 31;
                    int np = 0;
#pragma unroll
                    for (int s2 = 0; s2 < 16; s2++) np += aldi(&num_posS[s2 * BB + b]);
                    long long k64 = 3LL * np;
                    krem = (int)(k64 < (long long)(PP - 1) ? k64 : (long long)(PP - 1));
                    prefix = 0u;
                } else {
                    const ull st = gstate[((pass - 1) & 1) * 64 + task];
                    prefix = (unsigned)(st >> 32);
                    krem = (int)(st & 0xFFFFFFFFull);
                }
                if (krem > 0) {
                    unsigned cum = 0;
                    int sel = 0;
                    for (int byte = 255; byte >= 0; byte--) {
                        const unsigned h = s_bins[byte];
                        if (cum + h >= (unsigned)krem) { sel = byte; break; }
                        cum += h;
                    }
                    krem -= (int)cum;
                    prefix |= (unsigned)sel << shift;
                }
                gstate[(pass & 1) * 64 + task] = ((ull)prefix << 32) | (unsigned)krem;
            }
        }
        // v5 FIX: commit thread 0's gstate write to the whole block before the
        // next pass's accumulate (or the threshold-sum) reads it. Without this,
        // waves 1-3 raced ahead and read stale/uninitialized gstate.
        __syncthreads();
    }
    // threshold sum (state lives in gstate[1] after pass 3)
    for (int sb = bid; sb < NSB; sb += nblk) {
        const int task = sb >> 3, sub = sb & 7;
        const int arr = task >> 5, b = task & 31;
        int np = 0;
#pragma unroll
        for (int s2 = 0; s2 < 16; s2++) np += aldi(&num_posS[s2 * BB + b]);
        long long k64 = 3LL * np;
        const int k = (int)(k64 < (long long)(PP - 1) ? k64 : (long long)(PP - 1));
        if (k <= 0) continue;
        const unsigned t = (unsigned)(gstate[64 + task] >> 32);
        const float tf = __uint_as_float(t);
        const float* x = mining + ((size_t)arr * BB + b) * PP;
        float lsum = 0.0f;
        unsigned lcnt = 0;
#pragma unroll
        for (int j = 0; j < 12; j++) {
            const int i = j * 2048 + sub * 256 + tid;
            if (i < PP) {
                const float v = x[i];
                if (__float_as_uint(v) > t) { lsum += v; lcnt++; }
            }
        }
#pragma unroll
        for (int d = 32; d; d >>= 1) {
            lsum += __shfl_down(lsum, d);
            lcnt += __shfl_down(lcnt, d);
        }
        const int wv = tid >> 6;
        __syncthreads();
        if ((tid & 63) == 0) { s_ws[wv] = lsum; s_wc[wv] = lcnt; }
        __syncthreads();
        if (tid == 0) {
            float ts = s_ws[0] + s_ws[1] + s_ws[2] + s_ws[3];
            const unsigned tc = s_wc[0] + s_wc[1] + s_wc[2] + s_wc[3];
            // partial-sum trick: sum of per-sub (ts - tc*t) + (sub0: k*t)
            //   == total_sum + (k - total_cnt)*t
            float part = ts - (float)(int)tc * tf;
            if (sub == 0) part += (float)k * tf;
            atomicAdd(&acc[3 + arr], part);
        }
    }

    __threadfence();
    grid.sync();

    // ---------------- P4: final scalars (block 0, one wave) ----------------
    if (bid == 0 && tid < 64) {
        float sl = ald(&accS[tid * 32 + 0]) + ald(&accS[(tid + 64) * 32 + 0]);
        float so = ald(&accS[tid * 32 + 1]) + ald(&accS[(tid + 64) * 32 + 1]);
        float sc = ald(&accS[tid * 32 + 2]) + ald(&accS[(tid + 64) * 32 + 2]);
        int np_b = 0, k_b = 0;
        if (tid < BB) {
#pragma unroll
            for (int s2 = 0; s2 < 16; s2++) np_b += aldi(&num_posS[s2 * BB + tid]);
            long long k64 = 3LL * np_b;
            k_b = (int)(k64 < (long long)(PP - 1) ? k64 : (long long)(PP - 1));
        }
#pragma unroll
        for (int d = 32; d; d >>= 1) {
            sl += __shfl_down(sl, d);
            so += __shfl_down(so, d);
            sc += __shfl_down(sc, d);
            np_b += __shfl_down(np_b, d);
            k_b  += __shfl_down(k_b,  d);
        }
        if (tid == 0) {
            const float fN = (float)(np_b > 1 ? np_b : 1);
            const float fN1 = (float)(k_b > 1 ? k_b : 1);
            const float a3 = ald(&acc[3]);
            const float a4 = ald(&acc[4]);
            out[0] = sl / fN;
            out[1] = (sc + a4) / fN;
            out[2] = 0.4f * (so + a3) / fN1;
        }
    }
}

extern "C" void kernel_launch(void* const* d_in, const int* in_sizes, int n_in,
                              void* d_out, int out_size, void* d_ws, size_t ws_size,
                              hipStream_t stream) {
    const float* loc_data  = (const float*)d_in[0];
    const float* conf_data = (const float*)d_in[1];
    const float* obj_data  = (const float*)d_in[2];
    const float* priors    = (const float*)d_in[3];
    const float* truths    = (const float*)d_in[4];
    const int*   labels    = (const int*)d_in[5];
    float* out = (float*)d_out;

    // Workspace layout (float offsets from ws_f):
    // [0, 2BP)        mining: [0]=obj, [1]=c         (written before read)
    // S = 2BP:
    // [S, S+1024)     best_prior: 512 ull            (zeroed)
    // [S+1024,+512)   num_posS: 16 x 32 ints         (zeroed)
    // [S+1536,+16)    acc: [3]=neg_obj [4]=neg_c     (zeroed)
    // [S+2048,+4096)  accS: 128 stripes x 32 floats  (zeroed)
    // [S+6144,+65536) ghist: 4 passes x 64 x 256     (zeroed)
    // [S+71680,+256)  gstate: 2 x 64 ull             (zeroed)
    float* ws_f = (float*)d_ws;
    float* mining = ws_f;
    const size_t S = 2 * (size_t)BP;
    ull*      best_prior = (ull*)(ws_f + S);
    int*      num_posS   = (int*)(ws_f + S + 1024);
    float*    acc        = ws_f + S + 1536;
    float*    accS       = ws_f + S + 2048;
    unsigned* ghist      = (unsigned*)(ws_f + S + 6144);
    ull*      gstate     = (ull*)(ws_f + S + 71680);

    // zero best_prior..gstate in one shot: 71936 floats = 287744 B
    hipMemsetAsync((void*)best_prior, 0, 287744, stream);

    static int s_grid = 0;
    if (s_grid == 0) {
        int nb = 0;
        if (hipOccupancyMaxActiveBlocksPerMultiprocessor(&nb, k_mega, 256, 0)
                != hipSuccess || nb < 1)
            nb = 2;
        int ncu = 256;
        int dev = 0;
        hipDeviceProp_t prop;
        if (hipGetDevice(&dev) == hipSuccess &&
            hipGetDeviceProperties(&prop, dev) == hipSuccess &&
            prop.multiProcessorCount > 0)
            ncu = prop.multiProcessorCount;
        long long g = (long long)nb * (long long)ncu;
        s_grid = (int)(g < 1024 ? g : 1024);
    }

    void* args[] = {
        (void*)&conf_data, (void*)&obj_data, (void*)&loc_data, (void*)&priors,
        (void*)&truths, (void*)&labels, (void*)&best_prior, (void*)&mining,
        (void*)&num_posS, (void*)&acc, (void*)&accS, (void*)&ghist,
        (void*)&gstate, (void*)&out
    };
    hipLaunchCooperativeKernel((void*)k_mega, dim3(s_grid), dim3(256),
                               args, 0, stream);
}

// Round 6
// 1041.429 us; speedup vs baseline: 1.1358x; 1.1358x over previous
//
#include <hip/hip_runtime.h>
#include <hip/hip_bf16.h>
#include <math.h>

// Problem constants (fixed by the reference setup_inputs)
#define BB 32
#define PP 24564
#define OO 16
#define CC 81
#define BP (BB * PP)

typedef unsigned long long ull;

__device__ __forceinline__ float sl1(float x) {
    float ax = fabsf(x);
    return ax < 1.0f ? 0.5f * ax * ax : ax - 0.5f;
}

__device__ __forceinline__ float ald(const float* p) {
    return __hip_atomic_load(p, __ATOMIC_RELAXED, __HIP_MEMORY_SCOPE_AGENT);
}
__device__ __forceinline__ int aldi(const int* p) {
    return __hip_atomic_load(p, __ATOMIC_RELAXED, __HIP_MEMORY_SCOPE_AGENT);
}

// ---------------------------------------------------------------------------
// K1: one block per batch (32 blocks x 1024 thr). Scans ALL priors, block
// butterfly-reduce per truth, PLAIN STORE of best_prior (no atomics -> no
// zero-init). key = (iou_bits<<32) | (0xFFFFFFFF - p): max iou, tie min p.
// Block 0 also zeroes the accumulator region (12 KB) -- stream order
// guarantees this lands before k_ce starts. Replaces old k_match + memset.
// ---------------------------------------------------------------------------
__global__ __launch_bounds__(1024) void k_match(
        const float* __restrict__ priors, const float* __restrict__ truths,
        ull* __restrict__ best_prior /* [BB][OO] */,
        float* __restrict__ zero_base /* 3072 floats to clear */) {
    const int b = blockIdx.x;
    const int tid = threadIdx.x;
    __shared__ float tr[OO][4];
    __shared__ float tarea[OO];
    __shared__ ull red[16][OO];

    if (b == 0) {   // zero num_posS + acc + done + accS (12 KB)
        for (int i = tid; i < 3072; i += 1024) zero_base[i] = 0.0f;
    }

    if (tid < OO * 4) ((float*)tr)[tid] = truths[b * OO * 4 + tid];
    __syncthreads();
    if (tid < OO) tarea[tid] = (tr[tid][2] - tr[tid][0]) * (tr[tid][3] - tr[tid][1]);
    __syncthreads();

    float bpv[OO];
    int bpi[OO];
#pragma unroll
    for (int o = 0; o < OO; o++) { bpv[o] = -1.0f; bpi[o] = -1; }

    for (int p = tid; p < PP; p += 1024) {
        const float4 pr = ((const float4*)priors)[p];
        const float x1 = pr.x - pr.z * 0.5f, y1 = pr.y - pr.w * 0.5f;
        const float x2 = pr.x + pr.z * 0.5f, y2 = pr.y + pr.w * 0.5f;
        const float parea = (x2 - x1) * (y2 - y1);
#pragma unroll
        for (int o = 0; o < OO; o++) {
            const float lx = fmaxf(tr[o][0], x1), ly = fmaxf(tr[o][1], y1);
            const float rx = fminf(tr[o][2], x2), ry = fminf(tr[o][3], y2);
            const float iw = fmaxf(rx - lx, 0.0f), ih = fmaxf(ry - ly, 0.0f);
            const float inter = iw * ih;
            const float iou = inter / (tarea[o] + parea - inter);
            if (iou > bpv[o]) { bpv[o] = iou; bpi[o] = p; }   // p ascending
        }
    }

    const int wave = tid >> 6;
    const int lane = tid & 63;
#pragma unroll
    for (int o = 0; o < OO; o++) {
        ull key = (bpi[o] >= 0)
            ? (((ull)__float_as_uint(bpv[o]) << 32) |
               (ull)(0xFFFFFFFFu - (unsigned)bpi[o]))
            : 0ull;
#pragma unroll
        for (int d = 32; d; d >>= 1) {
            const ull other = __shfl_xor(key, d);
            key = (other > key) ? other : key;
        }
        if (lane == 0) red[wave][o] = key;
    }
    __syncthreads();
    if (tid < OO) {
        ull m = red[0][tid];
#pragma unroll
        for (int w = 1; w < 16; w++) {
            const ull k2 = red[w][tid];
            m = k2 > m ? k2 : m;
        }
        best_prior[b * OO + tid] = m;        // plain store, no init needed
    }
}

// ---------------------------------------------------------------------------
// K2: tile of 64 rows per block, conf staged through LDS with coalesced
// float4 loads. LSE by 4 threads/row; epilogue by wave 0, which recomputes
// its rows' best-truth match (16 IoUs) and applies the forced best-prior
// override from a 16-entry LDS table (ascending-o = last-writer-wins).
// Positive contributions wave-reduced; lane 0 issues <=5 atomics into
// striped accumulators. (Byte-identical to round-3 k_ce.)
// ---------------------------------------------------------------------------
__global__ __launch_bounds__(256) void k_ce(
        const float* __restrict__ conf, const float* __restrict__ obj,
        const float* __restrict__ loc, const float* __restrict__ priors,
        const float* __restrict__ truths, const int* __restrict__ labels,
        const ull* __restrict__ best_prior,
        float* __restrict__ mining_obj, float* __restrict__ mining_c,
        int* __restrict__ num_posS /* [8][BB] */,
        float* __restrict__ accS  /* [64][32] */) {
    const int tid = threadIdx.x;
    const int row0 = blockIdx.x * 64;            // BP == 64 * gridDim.x exactly
    const int b0 = row0 / PP;
    __shared__ float sconf[64 * CC];             // 20736 B
    __shared__ float slse[64];
    __shared__ float4 s_tr[2][OO];
    __shared__ float  s_ta[2][OO];
    __shared__ int    s_lb[2][OO];
    __shared__ unsigned s_fp[2][OO];

    const int nb = ((row0 - b0 * PP) + 64 > PP) ? 2 : 1;
    if (tid < nb * OO) {
        const int bb = tid >> 4, o = tid & 15;
        const float4 t = ((const float4*)truths)[(b0 + bb) * OO + o];
        s_tr[bb][o] = t;
        s_ta[bb][o] = (t.z - t.x) * (t.w - t.y);
        s_lb[bb][o] = labels[(b0 + bb) * OO + o];
        s_fp[bb][o] = 0xFFFFFFFFu -
            (unsigned)(best_prior[(b0 + bb) * OO + o] & 0xFFFFFFFFull);
    }

    const float4* src = (const float4*)(conf + (size_t)row0 * CC);
    float4* dst = (float4*)sconf;
    for (int i = tid; i < (64 * CC) / 4; i += 256) dst[i] = src[i];
    __syncthreads();

    const int r = tid >> 2;
    const int part = tid & 3;
    const float* rowp = sconf + r * CC;
    const int c0 = part * 20;
    const int c1 = (part == 3) ? CC : c0 + 20;   // 20,20,20,21
    float m = -INFINITY;
    for (int c = c0; c < c1; c++) m = fmaxf(m, rowp[c]);
    m = fmaxf(m, __shfl_xor(m, 1));
    m = fmaxf(m, __shfl_xor(m, 2));
    float s = 0.0f;
    for (int c = c0; c < c1; c++) s += __expf(rowp[c] - m);
    s += __shfl_xor(s, 1);
    s += __shfl_xor(s, 2);
    if (part == 0) slse[r] = m + __logf(s);
    __syncthreads();

    if (tid < 64) {                              // exactly wave 0
        const int row = row0 + tid;
        const int b = row / PP;
        const int lb_i = b - b0;
        const int p = row - b * PP;

        const float4 pr = ((const float4*)priors)[p];
        const float x1 = pr.x - pr.z * 0.5f, y1 = pr.y - pr.w * 0.5f;
        const float x2 = pr.x + pr.z * 0.5f, y2 = pr.y + pr.w * 0.5f;
        const float parea = (x2 - x1) * (y2 - y1);
        float best = -1.0f;
        int ti = 0;
#pragma unroll
        for (int o = 0; o < OO; o++) {
            const float4 t = s_tr[lb_i][o];
            const float lx = fmaxf(t.x, x1), ly = fmaxf(t.y, y1);
            const float rx = fminf(t.z, x2), ry = fminf(t.w, y2);
            const float iw = fmaxf(rx - lx, 0.0f), ih = fmaxf(ry - ly, 0.0f);
            const float inter = iw * ih;
            const float iou = inter / (s_ta[lb_i][o] + parea - inter);
            if (iou > best) { best = iou; ti = o; }
        }
        float ov = best;
#pragma unroll
        for (int o = 0; o < OO; o++) {           // ascending o = last-writer-wins
            if (s_fp[lb_i][o] == (unsigned)p) { ti = o; ov = 2.0f; }
        }

        const int lbl = s_lb[lb_i][ti];
        const int tgt = (ov < 0.5f) ? 0 : lbl;
        const float ce_c = slse[tid] - sconf[tid * CC + tgt];

        const float2 o2 = ((const float2*)obj)[row];
        const float mo = fmaxf(o2.x, o2.y);
        const float lse_o = mo + __logf(__expf(o2.x - mo) + __expf(o2.y - mo));
        const bool pos = tgt > 0;
        const float ce_o = lse_o - (pos ? o2.y : o2.x);

        mining_c[row]   = pos ? 0.0f : ce_c;
        mining_obj[row] = pos ? 0.0f : ce_o;

        float my_l = 0.0f, my_co = 0.0f, my_cc = 0.0f;
        if (pos) {
            my_co = ce_o;
            my_cc = ce_c;
            const float4 t = s_tr[lb_i][ti];
            const float gcx = ((t.x + t.z) * 0.5f - pr.x) / (0.1f * pr.z);
            const float gcy = ((t.y + t.w) * 0.5f - pr.y) / (0.1f * pr.w);
            const float gw = logf((t.z - t.x) / pr.z) / 0.2f;
            const float gh = logf((t.w - t.y) / pr.w) / 0.2f;
            const float4 ld = ((const float4*)loc)[row];
            my_l = sl1(ld.x - gcx) + sl1(ld.y - gcy) +
                   sl1(ld.z - gw) + sl1(ld.w - gh);
        }

        const ull mpos = __ballot(pos);
        const ull mb1  = __ballot(b != b0);
#pragma unroll
        for (int d = 32; d; d >>= 1) {
            my_l  += __shfl_down(my_l,  d);
            my_co += __shfl_down(my_co, d);
            my_cc += __shfl_down(my_cc, d);
        }
        if (tid == 0 && mpos) {
            const int cnt0 = __popcll(mpos & ~mb1);
            const int cnt1 = __popcll(mpos &  mb1);
            int* nps = num_posS + (blockIdx.x & 7) * BB;
            if (cnt0) atomicAdd(&nps[b0], cnt0);
            if (cnt1) atomicAdd(&nps[b0 + 1], cnt1);
            float* slot = accS + (size_t)(blockIdx.x & 63) * 32;
            atomicAdd(slot + 0, my_l);
            atomicAdd(slot + 1, my_co);
            atomicAdd(slot + 2, my_cc);
        }
    }
}

// ---------------------------------------------------------------------------
// K3: top-k sums via 4-pass radix select (per-wave privatized histograms),
// 64 blocks x 1024 thr: {obj,c} x 32 batches. LAST-BLOCK FINALIZE: a
// device-scope done-counter picks the 64th block to finish, which reduces
// the striped accumulators and writes out[0..2]. Replaces k_select+k_final.
// ---------------------------------------------------------------------------
__global__ __launch_bounds__(1024) void k_select_final(
        const float* __restrict__ mining /* [2][B][P] */,
        const int* __restrict__ num_posS /* [8][BB] */,
        float* __restrict__ acc /* [3]=neg_obj [4]=neg_c */,
        int* __restrict__ done_ctr,
        const float* __restrict__ accS /* [64][32] */,
        float* __restrict__ out) {
    const int arr = blockIdx.x >> 5;  // 0 = obj, 1 = c
    const int b = blockIdx.x & 31;
    const int tid = threadIdx.x;
    const int wv = tid >> 6;
    int np = 0;
#pragma unroll
    for (int s = 0; s < 8; s++) np += num_posS[s * BB + b];
    long long k64 = 3LL * np;
    const int k = (int)(k64 < (long long)(PP - 1) ? k64 : (long long)(PP - 1));

    __shared__ unsigned histw[16][256];   // 16 KiB, per-wave privatized
    __shared__ unsigned hist[256];
    __shared__ unsigned s_prefix;
    __shared__ int s_krem;
    __shared__ float wsum[16];
    __shared__ unsigned wcnt[16];
    __shared__ int s_last;

    if (k > 0) {
        const float* x = mining + ((size_t)arr * BB + b) * PP;
        if (tid == 0) { s_prefix = 0u; s_krem = k; }

        for (int shift = 24; shift >= 0; shift -= 8) {
            __syncthreads();
            for (int i = tid; i < 16 * 256; i += 1024) ((unsigned*)histw)[i] = 0u;
            const unsigned prefix = s_prefix;
            const unsigned pmask = (shift == 24) ? 0u : (0xFFFFFFFFu << (shift + 8));
            __syncthreads();
            for (int i = tid; i < PP; i += 1024) {
                const unsigned u = __float_as_uint(x[i]);
                if ((u & pmask) == prefix)
                    atomicAdd(&histw[wv][(u >> shift) & 255u], 1u);
            }
            __syncthreads();
            if (tid < 256) {
                unsigned s = 0;
#pragma unroll
                for (int w = 0; w < 16; w++) s += histw[w][tid];
                hist[tid] = s;
            }
            __syncthreads();
            if (tid == 0) {
                const int krem = s_krem;
                unsigned cum = 0;
                int sel = 0;
                for (int byte = 255; byte >= 0; byte--) {
                    const unsigned h = hist[byte];
                    if (cum + h >= (unsigned)krem) { sel = byte; break; }
                    cum += h;
                }
                s_krem = krem - (int)cum;
                s_prefix = prefix | ((unsigned)sel << shift);
            }
        }
        __syncthreads();

        const unsigned t = s_prefix;
        float lsum = 0.0f;
        unsigned lcnt = 0;
        for (int i = tid; i < PP; i += 1024) {
            const float v = x[i];
            if (__float_as_uint(v) > t) { lsum += v; lcnt++; }
        }
#pragma unroll
        for (int d = 32; d; d >>= 1) {
            lsum += __shfl_down(lsum, d);
            lcnt += __shfl_down(lcnt, d);
        }
        if ((tid & 63) == 0) { wsum[wv] = lsum; wcnt[wv] = lcnt; }
        __syncthreads();
        if (tid == 0) {
            float ts = 0.0f;
            unsigned tc = 0;
#pragma unroll
            for (int w = 0; w < 16; w++) { ts += wsum[w]; tc += wcnt[w]; }
            const float tsum = ts + (float)(k - (int)tc) * __uint_as_float(t);
            atomicAdd(&acc[3 + arr], tsum);
        }
    }

    // ---- completion protocol: last block to arrive finalizes ----
    __syncthreads();
    __threadfence();                       // release: acc/num_posS adds visible
    if (tid == 0) s_last = (atomicAdd(done_ctr, 1) == 63);
    __syncthreads();
    if (s_last) {
        __threadfence();                   // acquire side
        if (tid < 64) {
            float sl = ald(&accS[tid * 32 + 0]);
            float so = ald(&accS[tid * 32 + 1]);
            float sc = ald(&accS[tid * 32 + 2]);
            int np_b = 0, k_b = 0;
            if (tid < BB) {
#pragma unroll
                for (int s2 = 0; s2 < 8; s2++) np_b += aldi(&num_posS[s2 * BB + tid]);
                long long kk = 3LL * np_b;
                k_b = (int)(kk < (long long)(PP - 1) ? kk : (long long)(PP - 1));
            }
#pragma unroll
            for (int d = 32; d; d >>= 1) {
                sl += __shfl_down(sl, d);
                so += __shfl_down(so, d);
                sc += __shfl_down(sc, d);
                np_b += __shfl_down(np_b, d);
                k_b  += __shfl_down(k_b,  d);
            }
            if (tid == 0) {
                const float fN = (float)(np_b > 1 ? np_b : 1);
                const float fN1 = (float)(k_b > 1 ? k_b : 1);
                const float a3 = ald(&acc[3]);
                const float a4 = ald(&acc[4]);
                out[0] = sl / fN;
                out[1] = (sc + a4) / fN;
                out[2] = 0.4f * (so + a3) / fN1;
            }
        }
    }
}

extern "C" void kernel_launch(void* const* d_in, const int* in_sizes, int n_in,
                              void* d_out, int out_size, void* d_ws, size_t ws_size,
                              hipStream_t stream) {
    const float* loc_data  = (const float*)d_in[0];
    const float* conf_data = (const float*)d_in[1];
    const float* obj_data  = (const float*)d_in[2];
    const float* priors    = (const float*)d_in[3];
    const float* truths    = (const float*)d_in[4];
    const int*   labels    = (const int*)d_in[5];
    float* out = (float*)d_out;

    // Workspace layout (float offsets from ws_f):
    // [0, 2BP)              mining: [0]=obj, [1]=c
    // S = 2BP:
    // [S, S+1024)           best_prior: 512 ull (plain-stored, no init)
    // [S+1024, +256)        num_posS: 8 stripes x 32 ints     } zeroed by
    // [S+1280, +8)          acc ([3]=neg_obj [4]=neg_c)       } k_match
    // [S+1288]              done_ctr (int)                    } block 0
    // [S+2048, +2048)       accS: 64 stripes x 32 floats      } (3072 f)
    float* ws_f = (float*)d_ws;
    float* mining = ws_f;
    const size_t S = 2 * (size_t)BP;
    ull*   best_prior = (ull*)(ws_f + S);
    int*   num_posS   = (int*)(ws_f + S + 1024);
    float* acc        = ws_f + S + 1280;
    int*   done_ctr   = (int*)(ws_f + S + 1288);
    float* accS       = ws_f + S + 2048;
    float* zero_base  = ws_f + S + 1024;   // covers num_posS..accS (3072 f)

    k_match<<<BB, 1024, 0, stream>>>(priors, truths, best_prior, zero_base);

    k_ce<<<BP / 64, 256, 0, stream>>>(conf_data, obj_data, loc_data, priors,
                                      truths, labels, best_prior,
                                      mining /*obj*/, mining + BP /*c*/,
                                      num_posS, accS);

    k_select_final<<<64, 1024, 0, stream>>>(mining, num_posS, acc, done_ctr,
                                            accS, out);
}

// Round 7
// 467.666 us; speedup vs baseline: 2.5294x; 2.2269x over previous
//
#include <hip/hip_runtime.h>
#include <hip/hip_bf16.h>
#include <math.h>

// Problem constants (fixed by the reference setup_inputs)
#define BB 32
#define PP 24564
#define OO 16
#define CC 81
#define BP (BB * PP)
#define CHUNK 1024   // priors per k_match_a block; ceil(PP/CHUNK)=24 chunks

typedef unsigned long long ull;

__device__ __forceinline__ float sl1(float x) {
    float ax = fabsf(x);
    return ax < 1.0f ? 0.5f * ax * ax : ax - 0.5f;
}

// unaligned-by-16 (4B-aligned) float4 global load: conf row stride is 324 B
__device__ __forceinline__ float4 ld4u(const float* p) {
    float4 v;
    __builtin_memcpy(&v, p, 16);
    return v;
}

__device__ __forceinline__ float ald(const float* p) {
    return __hip_atomic_load(p, __ATOMIC_RELAXED, __HIP_MEMORY_SCOPE_AGENT);
}
__device__ __forceinline__ int aldi(const int* p) {
    return __hip_atomic_load(p, __ATOMIC_RELAXED, __HIP_MEMORY_SCOPE_AGENT);
}

// ---------------------------------------------------------------------------
// K1: per-(batch,truth) best prior via packed-key max:
//   key = (iou_bits << 32) | (0xFFFFFFFF - p) -> max iou, tie: smallest p.
// 256 thr x (24 chunks x 32 batches) blocks: bpv/bpi live in registers
// (round-6's 1024-thr variant spilled them to scratch: 593 us, VGPR=64).
// Wave shfl_xor butterfly, 16 global atomicMax per block (pre-zeroed dst).
// ---------------------------------------------------------------------------
__global__ __launch_bounds__(256) void k_match_a(
        const float* __restrict__ priors, const float* __restrict__ truths,
        ull* __restrict__ best_prior /* [BB][OO], pre-zeroed */) {
    const int b = blockIdx.y;
    const int p0 = blockIdx.x * CHUNK;
    const int tid = threadIdx.x;
    __shared__ float tr[OO][4];
    __shared__ float tarea[OO];
    __shared__ ull red[4][OO];
    if (tid < OO * 4) ((float*)tr)[tid] = truths[b * OO * 4 + tid];
    __syncthreads();
    if (tid < OO) tarea[tid] = (tr[tid][2] - tr[tid][0]) * (tr[tid][3] - tr[tid][1]);
    __syncthreads();

    float bpv[OO];
    int bpi[OO];
#pragma unroll
    for (int o = 0; o < OO; o++) { bpv[o] = -1.0f; bpi[o] = -1; }

    const int pend = (p0 + CHUNK < PP) ? p0 + CHUNK : PP;
    for (int p = p0 + tid; p < pend; p += 256) {
        const float4 pr = ((const float4*)priors)[p];
        const float x1 = pr.x - pr.z * 0.5f, y1 = pr.y - pr.w * 0.5f;
        const float x2 = pr.x + pr.z * 0.5f, y2 = pr.y + pr.w * 0.5f;
        const float parea = (x2 - x1) * (y2 - y1);
#pragma unroll
        for (int o = 0; o < OO; o++) {
            const float lx = fmaxf(tr[o][0], x1), ly = fmaxf(tr[o][1], y1);
            const float rx = fminf(tr[o][2], x2), ry = fminf(tr[o][3], y2);
            const float iw = fmaxf(rx - lx, 0.0f), ih = fmaxf(ry - ly, 0.0f);
            const float inter = iw * ih;
            const float iou = inter / (tarea[o] + parea - inter);
            if (iou > bpv[o]) { bpv[o] = iou; bpi[o] = p; }    // p ascending
        }
    }

    const int wave = tid >> 6;
    const int lane = tid & 63;
#pragma unroll
    for (int o = 0; o < OO; o++) {
        ull key = (bpi[o] >= 0)
            ? (((ull)__float_as_uint(bpv[o]) << 32) |
               (ull)(0xFFFFFFFFu - (unsigned)bpi[o]))
            : 0ull;
#pragma unroll
        for (int d = 32; d; d >>= 1) {
            const ull other = __shfl_xor(key, d);
            key = (other > key) ? other : key;
        }
        if (lane == 0) red[wave][o] = key;
    }
    __syncthreads();
    if (tid < OO) {
        const ull k0 = red[0][tid], k1 = red[1][tid];
        const ull k2 = red[2][tid], k3 = red[3][tid];
        ull m = k0 > k1 ? k0 : k1;
        const ull m2 = k2 > k3 ? k2 : k3;
        m = m > m2 ? m : m2;
        if (m != 0ull) atomicMax(&best_prior[b * OO + tid], m);
    }
}

// ---------------------------------------------------------------------------
// K2: one 64-row tile per block, NO LDS / NO barriers (structure lifted
// verbatim from the round-5 mega-kernel's P2, which passed correctness).
// 4 threads per row: direct-global float4 loads, in-register LSE with
// quartet shfl_xor; part==0 lane does match-recompute + epilogue; wave
// reduction + <=5 striped atomics per wave.
// ---------------------------------------------------------------------------
__global__ __launch_bounds__(256) void k_ce2(
        const float* __restrict__ conf, const float* __restrict__ obj,
        const float* __restrict__ loc, const float* __restrict__ priors,
        const float* __restrict__ truths, const int* __restrict__ labels,
        const ull* __restrict__ best_prior,
        float* __restrict__ mining /* [2][B][P]: [0]=obj [1]=c */,
        int* __restrict__ num_posS /* [8][BB] */,
        float* __restrict__ accS  /* [64][32] */) {
    const int tid = threadIdx.x;
    const int tile = blockIdx.x;                 // BP == 64 * gridDim.x
    const int row0 = tile * 64;
    const int r = tid >> 2;
    const int part = tid & 3;
    const int row = row0 + r;
    const float* rowp = conf + (size_t)row * CC;
    const int c0 = part * 20;

    const float4 v0 = ld4u(rowp + c0);
    const float4 v1 = ld4u(rowp + c0 + 4);
    const float4 v2 = ld4u(rowp + c0 + 8);
    const float4 v3 = ld4u(rowp + c0 + 12);
    const float4 v4 = ld4u(rowp + c0 + 16);
    const float ex = (part == 3) ? rowp[80] : 0.0f;

    float m = v0.x;
    m = fmaxf(m, v0.y); m = fmaxf(m, v0.z); m = fmaxf(m, v0.w);
    m = fmaxf(m, v1.x); m = fmaxf(m, v1.y); m = fmaxf(m, v1.z); m = fmaxf(m, v1.w);
    m = fmaxf(m, v2.x); m = fmaxf(m, v2.y); m = fmaxf(m, v2.z); m = fmaxf(m, v2.w);
    m = fmaxf(m, v3.x); m = fmaxf(m, v3.y); m = fmaxf(m, v3.z); m = fmaxf(m, v3.w);
    m = fmaxf(m, v4.x); m = fmaxf(m, v4.y); m = fmaxf(m, v4.z); m = fmaxf(m, v4.w);
    if (part == 3) m = fmaxf(m, ex);
    m = fmaxf(m, __shfl_xor(m, 1));
    m = fmaxf(m, __shfl_xor(m, 2));

    float s = 0.0f;
    s += __expf(v0.x - m); s += __expf(v0.y - m); s += __expf(v0.z - m); s += __expf(v0.w - m);
    s += __expf(v1.x - m); s += __expf(v1.y - m); s += __expf(v1.z - m); s += __expf(v1.w - m);
    s += __expf(v2.x - m); s += __expf(v2.y - m); s += __expf(v2.z - m); s += __expf(v2.w - m);
    s += __expf(v3.x - m); s += __expf(v3.y - m); s += __expf(v3.z - m); s += __expf(v3.w - m);
    s += __expf(v4.x - m); s += __expf(v4.y - m); s += __expf(v4.z - m); s += __expf(v4.w - m);
    if (part == 3) s += __expf(ex - m);
    s += __shfl_xor(s, 1);
    s += __shfl_xor(s, 2);
    const float lse = m + __logf(s);

    const int b = row / PP;
    bool pos = false;
    float my_l = 0.0f, my_co = 0.0f, my_cc = 0.0f;
    if (part == 0) {
        const int p = row - b * PP;
        const float4 pr = ((const float4*)priors)[p];
        const float x1 = pr.x - pr.z * 0.5f, y1 = pr.y - pr.w * 0.5f;
        const float x2 = pr.x + pr.z * 0.5f, y2 = pr.y + pr.w * 0.5f;
        const float parea = (x2 - x1) * (y2 - y1);
        float best = -1.0f;
        int ti = 0;
        const float4* trb = (const float4*)truths + b * OO;
#pragma unroll
        for (int o = 0; o < OO; o++) {
            const float4 t = trb[o];
            const float ta = (t.z - t.x) * (t.w - t.y);
            const float lx = fmaxf(t.x, x1), ly = fmaxf(t.y, y1);
            const float rx = fminf(t.z, x2), ry = fminf(t.w, y2);
            const float iw = fmaxf(rx - lx, 0.0f), ih = fmaxf(ry - ly, 0.0f);
            const float inter = iw * ih;
            const float iou = inter / (ta + parea - inter);
            if (iou > best) { best = iou; ti = o; }
        }
        float ov = best;
#pragma unroll
        for (int o = 0; o < OO; o++) {         // ascending o = last-writer-wins
            const unsigned fp = 0xFFFFFFFFu -
                (unsigned)(best_prior[b * OO + o] & 0xFFFFFFFFull);
            if (fp == (unsigned)p) { ti = o; ov = 2.0f; }
        }

        const int lbl = labels[b * OO + ti];
        const int tgt = (ov < 0.5f) ? 0 : lbl;
        const float ce_c = lse - rowp[tgt];

        const float2 o2 = ((const float2*)obj)[row];
        const float mo = fmaxf(o2.x, o2.y);
        const float lse_o = mo + __logf(__expf(o2.x - mo) + __expf(o2.y - mo));
        pos = tgt > 0;
        const float ce_o = lse_o - (pos ? o2.y : o2.x);

        mining[BP + row] = pos ? 0.0f : ce_c;   // mining_c
        mining[row]      = pos ? 0.0f : ce_o;   // mining_obj

        if (pos) {
            my_co = ce_o;
            my_cc = ce_c;
            const float4 t = trb[ti];
            const float gcx = ((t.x + t.z) * 0.5f - pr.x) / (0.1f * pr.z);
            const float gcy = ((t.y + t.w) * 0.5f - pr.y) / (0.1f * pr.w);
            const float gw = logf((t.z - t.x) / pr.z) / 0.2f;
            const float gh = logf((t.w - t.y) / pr.w) / 0.2f;
            const float4 ld = ((const float4*)loc)[row];
            my_l = sl1(ld.x - gcx) + sl1(ld.y - gcy) +
                   sl1(ld.z - gw) + sl1(ld.w - gh);
        }
    }

    const int lane = tid & 63;
    const int w = tid >> 6;
    const ull mpos = __ballot(pos);
    const int bw0 = __shfl(b, 0);
    const ull mb1 = __ballot(b != bw0);
#pragma unroll
    for (int d = 32; d; d >>= 1) {
        my_l  += __shfl_down(my_l,  d);
        my_co += __shfl_down(my_co, d);
        my_cc += __shfl_down(my_cc, d);
    }
    if (lane == 0 && mpos) {
        const int stripe = tile * 4 + w;
        const int cnt0 = __popcll(mpos & ~mb1);
        const int cnt1 = __popcll(mpos &  mb1);
        int* nps = num_posS + (stripe & 7) * BB;
        if (cnt0) atomicAdd(&nps[bw0], cnt0);
        if (cnt1) atomicAdd(&nps[bw0 + 1], cnt1);
        float* slot = accS + (size_t)(stripe & 63) * 32;
        atomicAdd(slot + 0, my_l);
        atomicAdd(slot + 1, my_co);
        atomicAdd(slot + 2, my_cc);
    }
}

// ---------------------------------------------------------------------------
// K3: top-k sums via 4-pass radix select (per-wave privatized histograms),
// 64 blocks x 1024 thr: {obj,c} x 32 batches. LAST-BLOCK FINALIZE: a
// device-scope done-counter picks the 64th block to finish, which reduces
// the striped accumulators and writes out[0..2].
// ---------------------------------------------------------------------------
__global__ __launch_bounds__(1024) void k_select_final(
        const float* __restrict__ mining /* [2][B][P] */,
        const int* __restrict__ num_posS /* [8][BB] */,
        float* __restrict__ acc /* [3]=neg_obj [4]=neg_c */,
        int* __restrict__ done_ctr,
        const float* __restrict__ accS /* [64][32] */,
        float* __restrict__ out) {
    const int arr = blockIdx.x >> 5;  // 0 = obj, 1 = c
    const int b = blockIdx.x & 31;
    const int tid = threadIdx.x;
    const int wv = tid >> 6;
    int np = 0;
#pragma unroll
    for (int s = 0; s < 8; s++) np += num_posS[s * BB + b];
    long long k64 = 3LL * np;
    const int k = (int)(k64 < (long long)(PP - 1) ? k64 : (long long)(PP - 1));

    __shared__ unsigned histw[16][256];   // 16 KiB, per-wave privatized
    __shared__ unsigned hist[256];
    __shared__ unsigned s_prefix;
    __shared__ int s_krem;
    __shared__ float wsum[16];
    __shared__ unsigned wcnt[16];
    __shared__ int s_last;

    if (k > 0) {
        const float* x = mining + ((size_t)arr * BB + b) * PP;
        if (tid == 0) { s_prefix = 0u; s_krem = k; }

        for (int shift = 24; shift >= 0; shift -= 8) {
            __syncthreads();
            for (int i = tid; i < 16 * 256; i += 1024) ((unsigned*)histw)[i] = 0u;
            const unsigned prefix = s_prefix;
            const unsigned pmask = (shift == 24) ? 0u : (0xFFFFFFFFu << (shift + 8));
            __syncthreads();
            for (int i = tid; i < PP; i += 1024) {
                const unsigned u = __float_as_uint(x[i]);
                if ((u & pmask) == prefix)
                    atomicAdd(&histw[wv][(u >> shift) & 255u], 1u);
            }
            __syncthreads();
            if (tid < 256) {
                unsigned s = 0;
#pragma unroll
                for (int w = 0; w < 16; w++) s += histw[w][tid];
                hist[tid] = s;
            }
            __syncthreads();
            if (tid == 0) {
                const int krem = s_krem;
                unsigned cum = 0;
                int sel = 0;
                for (int byte = 255; byte >= 0; byte--) {
                    const unsigned h = hist[byte];
                    if (cum + h >= (unsigned)krem) { sel = byte; break; }
                    cum += h;
                }
                s_krem = krem - (int)cum;
                s_prefix = prefix | ((unsigned)sel << shift);
            }
        }
        __syncthreads();

        const unsigned t = s_prefix;
        float lsum = 0.0f;
        unsigned lcnt = 0;
        for (int i = tid; i < PP; i += 1024) {
            const float v = x[i];
            if (__float_as_uint(v) > t) { lsum += v; lcnt++; }
        }
#pragma unroll
        for (int d = 32; d; d >>= 1) {
            lsum += __shfl_down(lsum, d);
            lcnt += __shfl_down(lcnt, d);
        }
        if ((tid & 63) == 0) { wsum[wv] = lsum; wcnt[wv] = lcnt; }
        __syncthreads();
        if (tid == 0) {
            float ts = 0.0f;
            unsigned tc = 0;
#pragma unroll
            for (int w = 0; w < 16; w++) { ts += wsum[w]; tc += wcnt[w]; }
            const float tsum = ts + (float)(k - (int)tc) * __uint_as_float(t);
            atomicAdd(&acc[3 + arr], tsum);
        }
    }

    // ---- completion protocol: last block to arrive finalizes ----
    __syncthreads();
    __threadfence();                       // release: acc adds visible
    if (tid == 0) s_last = (atomicAdd(done_ctr, 1) == 63);
    __syncthreads();
    if (s_last) {
        __threadfence();                   // acquire side
        if (tid < 64) {
            float sl = ald(&accS[tid * 32 + 0]);
            float so = ald(&accS[tid * 32 + 1]);
            float sc = ald(&accS[tid * 32 + 2]);
            int np_b = 0, k_b = 0;
            if (tid < BB) {
#pragma unroll
                for (int s2 = 0; s2 < 8; s2++) np_b += aldi(&num_posS[s2 * BB + tid]);
                long long kk = 3LL * np_b;
                k_b = (int)(kk < (long long)(PP - 1) ? kk : (long long)(PP - 1));
            }
#pragma unroll
            for (int d = 32; d; d >>= 1) {
                sl += __shfl_down(sl, d);
                so += __shfl_down(so, d);
                sc += __shfl_down(sc, d);
                np_b += __shfl_down(np_b, d);
                k_b  += __shfl_down(k_b,  d);
            }
            if (tid == 0) {
                const float fN = (float)(np_b > 1 ? np_b : 1);
                const float fN1 = (float)(k_b > 1 ? k_b : 1);
                const float a3 = ald(&acc[3]);
                const float a4 = ald(&acc[4]);
                out[0] = sl / fN;
                out[1] = (sc + a4) / fN;
                out[2] = 0.4f * (so + a3) / fN1;
            }
        }
    }
}

extern "C" void kernel_launch(void* const* d_in, const int* in_sizes, int n_in,
                              void* d_out, int out_size, void* d_ws, size_t ws_size,
                              hipStream_t stream) {
    const float* loc_data  = (const float*)d_in[0];
    const float* conf_data = (const float*)d_in[1];
    const float* obj_data  = (const float*)d_in[2];
    const float* priors    = (const float*)d_in[3];
    const float* truths    = (const float*)d_in[4];
    const int*   labels    = (const int*)d_in[5];
    float* out = (float*)d_out;

    // Workspace layout (float offsets from ws_f):
    // [0, 2BP)              mining: [0]=obj, [1]=c
    // S = 2BP:
    // [S, S+1024)           best_prior: 512 ull      } one 16 KB memset
    // [S+1024, +256)        num_posS: 8 x 32 ints    } covers S..S+4096
    // [S+1280, +8)          acc ([3]=neg_obj [4]=neg_c)
    // [S+1288]              done_ctr (int)
    // [S+2048, +2048)       accS: 64 stripes x 32 floats
    float* ws_f = (float*)d_ws;
    float* mining = ws_f;
    const size_t S = 2 * (size_t)BP;
    ull*   best_prior = (ull*)(ws_f + S);
    int*   num_posS   = (int*)(ws_f + S + 1024);
    float* acc        = ws_f + S + 1280;
    int*   done_ctr   = (int*)(ws_f + S + 1288);
    float* accS       = ws_f + S + 2048;

    hipMemsetAsync((void*)best_prior, 0, 16384, stream);

    dim3 mg((PP + CHUNK - 1) / CHUNK, BB);
    k_match_a<<<mg, 256, 0, stream>>>(priors, truths, best_prior);

    k_ce2<<<BP / 64, 256, 0, stream>>>(conf_data, obj_data, loc_data, priors,
                                       truths, labels, best_prior,
                                       mining, num_posS, accS);

    k_select_final<<<64, 1024, 0, stream>>>(mining, num_posS, acc, done_ctr,
                                            accS, out);
}